// Round 2
// baseline (1536.135 us; speedup 1.0000x reference)
//
#include <hip/hip_runtime.h>
#include <hip/hip_cooperative_groups.h>
#include <float.h>

namespace cg = cooperative_groups;

// ---------------- counting-sort + gather-reduce multi-aggregation ----------------
// ws layout (ints): counts[N] | offsets[N+1] | cursor[N] | partials[512] | perm[E]
//
// Round-2 structure: the whole sort pipeline (zero counts -> histogram ->
// 3-level exclusive scan -> atomic rank scatter) is ONE cooperative kernel
// with grid.sync() phase boundaries (removes 5 kernel-boundary drains and
// keeps counts/offsets/cursor L2-hot across phases). reduce is unchanged
// from round 1 for clean attribution. Fallback to the discrete-kernel path
// if cooperative launch is unavailable under graph capture.

#define COOP_BLOCKS 1024   // 4 blocks/CU needed -> trivially co-resident
#define BLK 256

__global__ void __launch_bounds__(256, 4) fused_sort(
    const int* __restrict__ dst, int stride,
    int* __restrict__ counts, int* __restrict__ offsets, int* __restrict__ cursor,
    int* __restrict__ partials, int* __restrict__ perm,
    int N, int E, int NB_N)
{
    cg::grid_group grid = cg::this_grid();
    const int tid = blockIdx.x * BLK + threadIdx.x;
    const int nthreads = gridDim.x * BLK;

    // ---- phase 0: zero counts ----
    for (int i = tid; i < N; i += nthreads) counts[i] = 0;
    __threadfence();
    grid.sync();

    // ---- phase 1: histogram (16B dst loads: 2 int64 edges per iter) ----
    if (stride == 2) {
        const int4* d4 = (const int4*)dst;         // {lo0,hi0,lo1,hi1}
        int npair = E >> 1;
        for (int p = tid; p < npair; p += nthreads) {
            int4 v = d4[p];
            atomicAdd(&counts[v.x], 1);
            atomicAdd(&counts[v.z], 1);
        }
        for (int e = (npair << 1) + tid; e < E; e += nthreads)   // odd-E tail
            atomicAdd(&counts[(int)((const long long*)dst)[e]], 1);
    } else {
        for (int e = tid; e < E; e += nthreads)
            atomicAdd(&counts[dst[e]], 1);
    }
    __threadfence();
    grid.sync();

    // ---- phase 2: per-256-chunk exclusive scan; chunk c -> block c ----
    {
        int c = blockIdx.x;
        if (c < NB_N) {
            __shared__ int s[BLK];
            int t = threadIdx.x;
            int i = c * BLK + t;
            int x = (i < N) ? counts[i] : 0;
            s[t] = x;
            __syncthreads();
            for (int o = 1; o < BLK; o <<= 1) {
                int y = (t >= o) ? s[t - o] : 0;
                __syncthreads();
                s[t] += y;
                __syncthreads();
            }
            if (i < N) offsets[i] = s[t] - x;      // exclusive within chunk
            if (t == BLK - 1) partials[c] = s[t];  // chunk total
        }
    }
    __threadfence();
    grid.sync();

    // ---- phase 3: exclusive scan of up to 512 chunk totals (block 0, pair scan) ----
    if (blockIdx.x == 0) {
        __shared__ int a[BLK];
        int t = threadIdx.x;
        int i0 = 2 * t, i1 = 2 * t + 1;
        int x0 = (i0 < NB_N) ? partials[i0] : 0;
        int x1 = (i1 < NB_N) ? partials[i1] : 0;
        a[t] = x0 + x1;
        __syncthreads();
        for (int o = 1; o < BLK; o <<= 1) {
            int y = (t >= o) ? a[t - o] : 0;
            __syncthreads();
            a[t] += y;
            __syncthreads();
        }
        int excl = a[t] - (x0 + x1);               // exclusive prefix of pair
        if (i0 < NB_N) partials[i0] = excl;
        if (i1 < NB_N) partials[i1] = excl + x0;
    }
    __threadfence();
    grid.sync();

    // ---- phase 4: add chunk bases; init cursor; offsets[N]=E ----
    for (int i = tid; i < N; i += nthreads) {
        int off = offsets[i] + partials[i >> 8];
        offsets[i] = off;
        cursor[i] = off;
    }
    if (tid == 0) offsets[N] = E;
    __threadfence();
    grid.sync();

    // ---- phase 5: rank scatter (16B dst loads) ----
    if (stride == 2) {
        const int4* d4 = (const int4*)dst;
        int npair = E >> 1;
        for (int p = tid; p < npair; p += nthreads) {
            int4 v = d4[p];
            int e0 = 2 * p, e1 = 2 * p + 1;
            int p0 = atomicAdd(&cursor[v.x], 1);
            perm[p0] = e0;
            int p1 = atomicAdd(&cursor[v.z], 1);
            perm[p1] = e1;
        }
        for (int e = (npair << 1) + tid; e < E; e += nthreads) {
            int n = (int)((const long long*)dst)[e];
            int pos = atomicAdd(&cursor[n], 1);
            perm[pos] = e;
        }
    } else {
        for (int e = tid; e < E; e += nthreads) {
            int n = dst[e];
            int pos = atomicAdd(&cursor[n], 1);
            perm[pos] = e;
        }
    }
}

// ---------------- fallback discrete kernels (round-1 proven path) ----------------

__global__ void zero_counts(int* __restrict__ counts, int N) {
    int i = blockIdx.x * 256 + threadIdx.x;
    if (i < N) counts[i] = 0;
}

__global__ void hist(const int* __restrict__ dst, int stride, int* __restrict__ counts, int E) {
    int e = blockIdx.x * 256 + threadIdx.x;
    if (e < E) {
        int n = (stride == 2) ? (int)((const long long*)dst)[e] : dst[e];
        atomicAdd(&counts[n], 1);
    }
}

__global__ void scan1(const int* __restrict__ counts, int* __restrict__ offsets,
                      int* __restrict__ partials, int N) {
    __shared__ int s[256];
    int t = threadIdx.x;
    int i = blockIdx.x * 256 + t;
    int x = (i < N) ? counts[i] : 0;
    s[t] = x;
    __syncthreads();
    for (int o = 1; o < 256; o <<= 1) {
        int y = (t >= o) ? s[t - o] : 0;
        __syncthreads();
        s[t] += y;
        __syncthreads();
    }
    if (i < N) offsets[i] = s[t] - x;
    if (t == 255) partials[blockIdx.x] = s[255];
}

__global__ void scan2(int* __restrict__ partials, int NB) {
    __shared__ int s[512];
    int t = threadIdx.x;
    int x = (t < NB) ? partials[t] : 0;
    s[t] = x;
    __syncthreads();
    for (int o = 1; o < 512; o <<= 1) {
        int y = (t >= o) ? s[t - o] : 0;
        __syncthreads();
        s[t] += y;
        __syncthreads();
    }
    if (t < NB) partials[t] = s[t] - x;
}

__global__ void scan3(int* __restrict__ offsets, const int* __restrict__ partials,
                      int* __restrict__ cursor, int N, int E) {
    int i = blockIdx.x * 256 + threadIdx.x;
    if (i < N) {
        int off = offsets[i] + partials[blockIdx.x];
        offsets[i] = off;
        cursor[i] = off;
    }
    if (i == 0) offsets[N] = E;
}

__global__ void permscatter(const int* __restrict__ dst, int stride,
                            int* __restrict__ cursor, int* __restrict__ perm, int E) {
    int e = blockIdx.x * 256 + threadIdx.x;
    if (e < E) {
        int n = (stride == 2) ? (int)((const long long*)dst)[e] : dst[e];
        int pos = atomicAdd(&cursor[n], 1);
        perm[pos] = e;
    }
}

// ---------------- gather-reduce (unchanged from round 1) ----------------
// One wave per node; lane = feature. 64-edge chunked eid load (coalesced) +
// shuffle broadcast + 4-wide independent row gathers.
__global__ void reduce(const float* __restrict__ msg, const int* __restrict__ perm,
                       const int* __restrict__ offsets, float* __restrict__ out, int N) {
    int node = blockIdx.x * 4 + (threadIdx.x >> 6);
    if (node >= N) return;
    int lane = threadIdx.x & 63;
    int beg = offsets[node];
    int end = offsets[node + 1];

    float s0 = 0.f, s1 = 0.f, s2 = 0.f, s3 = 0.f;
    float q0 = 0.f, q1 = 0.f, q2 = 0.f, q3 = 0.f;
    float m0 = -FLT_MAX, m1 = -FLT_MAX, m2 = -FLT_MAX, m3 = -FLT_MAX;

    const float* mp = msg + lane;

    for (int base = beg; base < end; base += 64) {
        int cnt = end - base;
        if (cnt > 64) cnt = 64;
        int idx = base + lane;
        if (idx >= end) idx = end - 1;          // clamp: wave-uniform loop bound
        int eid_l = perm[idx];

        int j = 0;
        for (; j + 4 <= cnt; j += 4) {
            int e0 = __shfl(eid_l, j + 0);
            int e1 = __shfl(eid_l, j + 1);
            int e2 = __shfl(eid_l, j + 2);
            int e3 = __shfl(eid_l, j + 3);
            float v0 = mp[(long long)e0 << 6];
            float v1 = mp[(long long)e1 << 6];
            float v2 = mp[(long long)e2 << 6];
            float v3 = mp[(long long)e3 << 6];
            s0 += v0; q0 += v0 * v0; m0 = fmaxf(m0, v0);
            s1 += v1; q1 += v1 * v1; m1 = fmaxf(m1, v1);
            s2 += v2; q2 += v2 * v2; m2 = fmaxf(m2, v2);
            s3 += v3; q3 += v3 * v3; m3 = fmaxf(m3, v3);
        }
        for (; j < cnt; ++j) {
            int e = __shfl(eid_l, j);
            float v = mp[(long long)e << 6];
            s0 += v; q0 += v * v; m0 = fmaxf(m0, v);
        }
    }

    float s  = (s0 + s1) + (s2 + s3);
    float sq = (q0 + q1) + (q2 + q3);
    float mx = fmaxf(fmaxf(m0, m1), fmaxf(m2, m3));

    float deg  = fmaxf((float)(end - beg), 1.0f);
    float mean = s / deg;
    float var  = fmaxf(sq / deg - mean * mean, 0.0f);
    float mxo  = (end > beg) ? mx : 0.0f;       // empty segment -> 0

    float* base_out = out + (long long)node * 256;
    base_out[lane]       = s;
    base_out[64 + lane]  = mean;
    base_out[128 + lane] = mxo;
    base_out[192 + lane] = sqrtf(var + 1e-8f);
}

extern "C" void kernel_launch(void* const* d_in, const int* in_sizes, int n_in,
                              void* d_out, int out_size, void* d_ws, size_t ws_size,
                              hipStream_t stream) {
    const float* msg = (const float*)d_in[0];
    const int*   dst = (const int*)d_in[1];
    float* out = (float*)d_out;

    int E = in_sizes[0] / 64;                 // 1,600,000
    int N = out_size / 256;                   // 100,000
    int stride = (in_sizes[1] == 2 * E) ? 2 : 1;   // int64-as-int32-pairs defense

    int* counts   = (int*)d_ws;
    int* offsets  = counts + N;               // N+1
    int* cursor   = offsets + N + 1;
    int* partials = cursor + N;               // 512
    int* perm     = partials + 512;           // E

    int NB_N = (N + 255) / 256;               // 391 (<= 512 required for pair scan)
    int NB_E = (E + 255) / 256;

    // ---- single cooperative sort kernel; fallback to discrete path on error ----
    {
        const int* dst_a = dst; int stride_a = stride;
        int* counts_a = counts; int* offsets_a = offsets; int* cursor_a = cursor;
        int* partials_a = partials; int* perm_a = perm;
        int N_a = N, E_a = E, NB_a = NB_N;
        void* args[] = { (void*)&dst_a, (void*)&stride_a, (void*)&counts_a,
                         (void*)&offsets_a, (void*)&cursor_a, (void*)&partials_a,
                         (void*)&perm_a, (void*)&N_a, (void*)&E_a, (void*)&NB_a };
        hipError_t err = hipLaunchCooperativeKernel((const void*)fused_sort,
                                                    dim3(COOP_BLOCKS), dim3(BLK),
                                                    args, 0, stream);
        if (err != hipSuccess) {
            // fallback: proven round-1 pipeline
            zero_counts<<<NB_N, 256, 0, stream>>>(counts, N);
            hist<<<NB_E, 256, 0, stream>>>(dst, stride, counts, E);
            scan1<<<NB_N, 256, 0, stream>>>(counts, offsets, partials, N);
            scan2<<<1, 512, 0, stream>>>(partials, NB_N);
            scan3<<<NB_N, 256, 0, stream>>>(offsets, partials, cursor, N, E);
            permscatter<<<NB_E, 256, 0, stream>>>(dst, stride, cursor, perm, E);
        }
    }

    reduce<<<(N + 3) / 4, 256, 0, stream>>>(msg, perm, offsets, out, N);
}

// Round 3
// 664.324 us; speedup vs baseline: 2.3123x; 2.3123x over previous
//
#include <hip/hip_runtime.h>
#include <float.h>

// ---------------- counting-sort + gather-reduce multi-aggregation ----------------
// Round-3 structure: single-atomic-pass counting sort.
//   hist_rank:  rank[e] = atomicAdd(&counts[dst[e]], 1)   (counts end as degrees)
//   scan1/2:    chunk-local exclusive scan of counts + chunk totals scan
//   scatter:    perm[lofs[n] + partials[n>>8] + rank[e]] = e     (NO atomics)
//   reduce:     beg = lofs[node] + partials[node>>8]; deg = counts[node]
// ws layout (ints): counts[N] | lofs[N] | partials[512] | perm[E] | rank[E]
// Fallback (ws too small): round-1 two-atomic-pass path using cursor[N] in
// place of rank[E]; same scan1/scan2/reduce kernels.

#define BLK 256

__global__ void zero_counts(int* __restrict__ counts, int N) {
    int i = blockIdx.x * BLK + threadIdx.x;
    if (i < N) counts[i] = 0;
}

// ---- rank path: one atomic pass, rank persisted ----
__global__ void hist_rank(const int* __restrict__ dst, int stride,
                          int* __restrict__ counts, int* __restrict__ rank, int E) {
    int e = blockIdx.x * BLK + threadIdx.x;
    if (e < E) {
        int n = (stride == 2) ? (int)((const long long*)dst)[e] : dst[e];
        rank[e] = atomicAdd(&counts[n], 1);
    }
}

__global__ void scatter_rank(const int* __restrict__ dst, int stride,
                             const int* __restrict__ lofs, const int* __restrict__ partials,
                             const int* __restrict__ rank, int* __restrict__ perm, int E) {
    int e = blockIdx.x * BLK + threadIdx.x;
    if (e < E) {
        int n = (stride == 2) ? (int)((const long long*)dst)[e] : dst[e];
        perm[lofs[n] + partials[n >> 8] + rank[e]] = e;   // atomic-free scatter
    }
}

// ---- shared scans ----
// Per-chunk exclusive scan; lofs = chunk-local exclusive, partials = chunk totals.
__global__ void scan1(const int* __restrict__ counts, int* __restrict__ lofs,
                      int* __restrict__ partials, int N) {
    __shared__ int s[BLK];
    int t = threadIdx.x;
    int i = blockIdx.x * BLK + t;
    int x = (i < N) ? counts[i] : 0;
    s[t] = x;
    __syncthreads();
    for (int o = 1; o < BLK; o <<= 1) {
        int y = (t >= o) ? s[t - o] : 0;
        __syncthreads();
        s[t] += y;
        __syncthreads();
    }
    if (i < N) lofs[i] = s[t] - x;             // exclusive within chunk
    if (t == BLK - 1) partials[blockIdx.x] = s[t];
}

// Single-block exclusive scan of up to 512 chunk totals.
__global__ void scan2(int* __restrict__ partials, int NB) {
    __shared__ int s[512];
    int t = threadIdx.x;
    int x = (t < NB) ? partials[t] : 0;
    s[t] = x;
    __syncthreads();
    for (int o = 1; o < 512; o <<= 1) {
        int y = (t >= o) ? s[t - o] : 0;
        __syncthreads();
        s[t] += y;
        __syncthreads();
    }
    if (t < NB) partials[t] = s[t] - x;        // exclusive
}

// ---- fallback path (two atomic passes, cursor in place of rank) ----
__global__ void hist(const int* __restrict__ dst, int stride, int* __restrict__ counts, int E) {
    int e = blockIdx.x * BLK + threadIdx.x;
    if (e < E) {
        int n = (stride == 2) ? (int)((const long long*)dst)[e] : dst[e];
        atomicAdd(&counts[n], 1);
    }
}

__global__ void cursor_init(const int* __restrict__ lofs, const int* __restrict__ partials,
                            int* __restrict__ cursor, int N) {
    int i = blockIdx.x * BLK + threadIdx.x;
    if (i < N) cursor[i] = lofs[i] + partials[i >> 8];
}

__global__ void permscatter(const int* __restrict__ dst, int stride,
                            int* __restrict__ cursor, int* __restrict__ perm, int E) {
    int e = blockIdx.x * BLK + threadIdx.x;
    if (e < E) {
        int n = (stride == 2) ? (int)((const long long*)dst)[e] : dst[e];
        int pos = atomicAdd(&cursor[n], 1);
        perm[pos] = e;
    }
}

// ---- gather-reduce: one wave per node; lane = feature ----
// Coalesced 64-edge eid chunk + shuffle broadcast + 8 independent 256B row
// loads in flight per wave.
__global__ void reduce(const float* __restrict__ msg, const int* __restrict__ perm,
                       const int* __restrict__ lofs, const int* __restrict__ partials,
                       const int* __restrict__ counts, float* __restrict__ out, int N) {
    int node = blockIdx.x * 4 + (threadIdx.x >> 6);
    if (node >= N) return;
    int lane = threadIdx.x & 63;
    int beg = lofs[node] + partials[node >> 8];
    int deg_i = counts[node];
    int end = beg + deg_i;

    float s0 = 0.f, s1 = 0.f, s2 = 0.f, s3 = 0.f;
    float q0 = 0.f, q1 = 0.f, q2 = 0.f, q3 = 0.f;
    float m0 = -FLT_MAX, m1 = -FLT_MAX, m2 = -FLT_MAX, m3 = -FLT_MAX;

    const float* mp = msg + lane;

    for (int base = beg; base < end; base += 64) {
        int cnt = end - base;
        if (cnt > 64) cnt = 64;
        int idx = base + lane;
        if (idx >= end) idx = end - 1;          // clamp: wave-uniform loop bound
        int eid_l = perm[idx];

        int j = 0;
        for (; j + 8 <= cnt; j += 8) {          // 8 outstanding row loads
            int e0 = __shfl(eid_l, j + 0);
            int e1 = __shfl(eid_l, j + 1);
            int e2 = __shfl(eid_l, j + 2);
            int e3 = __shfl(eid_l, j + 3);
            int e4 = __shfl(eid_l, j + 4);
            int e5 = __shfl(eid_l, j + 5);
            int e6 = __shfl(eid_l, j + 6);
            int e7 = __shfl(eid_l, j + 7);
            float v0 = mp[(long long)e0 << 6];
            float v1 = mp[(long long)e1 << 6];
            float v2 = mp[(long long)e2 << 6];
            float v3 = mp[(long long)e3 << 6];
            float v4 = mp[(long long)e4 << 6];
            float v5 = mp[(long long)e5 << 6];
            float v6 = mp[(long long)e6 << 6];
            float v7 = mp[(long long)e7 << 6];
            s0 += v0; q0 += v0 * v0; m0 = fmaxf(m0, v0);
            s1 += v1; q1 += v1 * v1; m1 = fmaxf(m1, v1);
            s2 += v2; q2 += v2 * v2; m2 = fmaxf(m2, v2);
            s3 += v3; q3 += v3 * v3; m3 = fmaxf(m3, v3);
            s0 += v4; q0 += v4 * v4; m0 = fmaxf(m0, v4);
            s1 += v5; q1 += v5 * v5; m1 = fmaxf(m1, v5);
            s2 += v6; q2 += v6 * v6; m2 = fmaxf(m2, v6);
            s3 += v7; q3 += v7 * v7; m3 = fmaxf(m3, v7);
        }
        for (; j + 4 <= cnt; j += 4) {
            int e0 = __shfl(eid_l, j + 0);
            int e1 = __shfl(eid_l, j + 1);
            int e2 = __shfl(eid_l, j + 2);
            int e3 = __shfl(eid_l, j + 3);
            float v0 = mp[(long long)e0 << 6];
            float v1 = mp[(long long)e1 << 6];
            float v2 = mp[(long long)e2 << 6];
            float v3 = mp[(long long)e3 << 6];
            s0 += v0; q0 += v0 * v0; m0 = fmaxf(m0, v0);
            s1 += v1; q1 += v1 * v1; m1 = fmaxf(m1, v1);
            s2 += v2; q2 += v2 * v2; m2 = fmaxf(m2, v2);
            s3 += v3; q3 += v3 * v3; m3 = fmaxf(m3, v3);
        }
        for (; j < cnt; ++j) {
            int e = __shfl(eid_l, j);
            float v = mp[(long long)e << 6];
            s0 += v; q0 += v * v; m0 = fmaxf(m0, v);
        }
    }

    float s  = (s0 + s1) + (s2 + s3);
    float sq = (q0 + q1) + (q2 + q3);
    float mx = fmaxf(fmaxf(m0, m1), fmaxf(m2, m3));

    float deg  = fmaxf((float)deg_i, 1.0f);
    float mean = s / deg;
    float var  = fmaxf(sq / deg - mean * mean, 0.0f);
    float mxo  = (deg_i > 0) ? mx : 0.0f;       // empty segment -> 0

    float* base_out = out + (long long)node * 256;
    base_out[lane]       = s;
    base_out[64 + lane]  = mean;
    base_out[128 + lane] = mxo;
    base_out[192 + lane] = sqrtf(var + 1e-8f);
}

extern "C" void kernel_launch(void* const* d_in, const int* in_sizes, int n_in,
                              void* d_out, int out_size, void* d_ws, size_t ws_size,
                              hipStream_t stream) {
    const float* msg = (const float*)d_in[0];
    const int*   dst = (const int*)d_in[1];
    float* out = (float*)d_out;

    int E = in_sizes[0] / 64;                 // 1,600,000
    int N = out_size / 256;                   // 100,000
    int stride = (in_sizes[1] == 2 * E) ? 2 : 1;   // int64-as-int32-pairs defense

    int* counts   = (int*)d_ws;
    int* lofs     = counts + N;
    int* partials = lofs + N;                 // 512
    int* perm     = partials + 512;           // E
    int* extra    = perm + E;                 // rank[E] (rank path) or cursor[N] (fallback)

    int NB_N = (N + BLK - 1) / BLK;           // 391 (<= 512 required for scan2)
    int NB_E = (E + BLK - 1) / BLK;

    size_t need_rank = ((size_t)2 * N + 512 + (size_t)2 * E) * sizeof(int);

    zero_counts<<<NB_N, BLK, 0, stream>>>(counts, N);

    if (ws_size >= need_rank) {
        // ---- single-atomic-pass counting sort ----
        int* rank = extra;
        hist_rank<<<NB_E, BLK, 0, stream>>>(dst, stride, counts, rank, E);
        scan1<<<NB_N, BLK, 0, stream>>>(counts, lofs, partials, N);
        scan2<<<1, 512, 0, stream>>>(partials, NB_N);
        scatter_rank<<<NB_E, BLK, 0, stream>>>(dst, stride, lofs, partials, rank, perm, E);
    } else {
        // ---- fallback: two-atomic-pass path ----
        int* cursor = extra;
        hist<<<NB_E, BLK, 0, stream>>>(dst, stride, counts, E);
        scan1<<<NB_N, BLK, 0, stream>>>(counts, lofs, partials, N);
        scan2<<<1, 512, 0, stream>>>(partials, NB_N);
        cursor_init<<<NB_N, BLK, 0, stream>>>(lofs, partials, cursor, N);
        permscatter<<<NB_E, BLK, 0, stream>>>(dst, stride, cursor, perm, E);
    }

    reduce<<<(N + 3) / 4, BLK, 0, stream>>>(msg, perm, lofs, partials, counts, out, N);
}

// Round 4
// 642.195 us; speedup vs baseline: 2.3920x; 1.0345x over previous
//
#include <hip/hip_runtime.h>
#include <float.h>

// ---------------- counting-sort + gather-reduce multi-aggregation ----------------
// Round-4 structure: same single-atomic-pass counting sort as round 3, plus:
//   * hist_rank / scatter_rank process 2 edges/thread (16B dst loads, int2 rank)
//   * reduce gathers with float4 lanes: 16 lanes per 256B row -> 4 edges per
//     VMEM instruction, 8 edges (8KB) in flight per wave; cross-lane butterfly
//     (xor 16,32) folds the 4 edge-slots; nontemporal msg loads / out stores.
// ws layout (ints): counts[N] | lofs[N] | partials[512] | perm[E] | rank[E]

#define BLK 256

typedef float v4f __attribute__((ext_vector_type(4)));

__device__ __forceinline__ v4f fmax4(v4f a, v4f b) {
    v4f r;
    r.x = fmaxf(a.x, b.x); r.y = fmaxf(a.y, b.y);
    r.z = fmaxf(a.z, b.z); r.w = fmaxf(a.w, b.w);
    return r;
}

__global__ void zero_counts(int* __restrict__ counts, int N) {
    int i = blockIdx.x * BLK + threadIdx.x;
    if (i < N) counts[i] = 0;
}

// ---- rank path: one atomic pass, 2 edges/thread ----
__global__ void hist_rank(const int* __restrict__ dst, int stride,
                          int* __restrict__ counts, int* __restrict__ rank, int E) {
    int p = blockIdx.x * BLK + threadIdx.x;
    int npair = E >> 1;
    if (p < npair) {
        int n0, n1;
        if (stride == 2) { int4 v = ((const int4*)dst)[p]; n0 = v.x; n1 = v.z; }
        else             { int2 v = ((const int2*)dst)[p]; n0 = v.x; n1 = v.y; }
        int r0 = atomicAdd(&counts[n0], 1);
        int r1 = atomicAdd(&counts[n1], 1);
        *(int2*)(rank + 2 * p) = make_int2(r0, r1);
    }
    if ((E & 1) && p == npair) {                 // odd-E tail edge
        int e = E - 1;
        int n = (stride == 2) ? (int)((const long long*)dst)[e] : dst[e];
        rank[e] = atomicAdd(&counts[n], 1);
    }
}

__global__ void scatter_rank(const int* __restrict__ dst, int stride,
                             const int* __restrict__ lofs, const int* __restrict__ partials,
                             const int* __restrict__ rank, int* __restrict__ perm, int E) {
    int p = blockIdx.x * BLK + threadIdx.x;
    int npair = E >> 1;
    if (p < npair) {
        int n0, n1;
        if (stride == 2) { int4 v = ((const int4*)dst)[p]; n0 = v.x; n1 = v.z; }
        else             { int2 v = ((const int2*)dst)[p]; n0 = v.x; n1 = v.y; }
        int2 r = *(const int2*)(rank + 2 * p);
        perm[lofs[n0] + partials[n0 >> 8] + r.x] = 2 * p;       // atomic-free
        perm[lofs[n1] + partials[n1 >> 8] + r.y] = 2 * p + 1;
    }
    if ((E & 1) && p == npair) {
        int e = E - 1;
        int n = (stride == 2) ? (int)((const long long*)dst)[e] : dst[e];
        perm[lofs[n] + partials[n >> 8] + rank[e]] = e;
    }
}

// ---- scans (unchanged) ----
__global__ void scan1(const int* __restrict__ counts, int* __restrict__ lofs,
                      int* __restrict__ partials, int N) {
    __shared__ int s[BLK];
    int t = threadIdx.x;
    int i = blockIdx.x * BLK + t;
    int x = (i < N) ? counts[i] : 0;
    s[t] = x;
    __syncthreads();
    for (int o = 1; o < BLK; o <<= 1) {
        int y = (t >= o) ? s[t - o] : 0;
        __syncthreads();
        s[t] += y;
        __syncthreads();
    }
    if (i < N) lofs[i] = s[t] - x;             // exclusive within chunk
    if (t == BLK - 1) partials[blockIdx.x] = s[t];
}

__global__ void scan2(int* __restrict__ partials, int NB) {
    __shared__ int s[512];
    int t = threadIdx.x;
    int x = (t < NB) ? partials[t] : 0;
    s[t] = x;
    __syncthreads();
    for (int o = 1; o < 512; o <<= 1) {
        int y = (t >= o) ? s[t - o] : 0;
        __syncthreads();
        s[t] += y;
        __syncthreads();
    }
    if (t < NB) partials[t] = s[t] - x;        // exclusive
}

// ---- fallback path (two atomic passes; only if ws too small for rank[E]) ----
__global__ void hist(const int* __restrict__ dst, int stride, int* __restrict__ counts, int E) {
    int e = blockIdx.x * BLK + threadIdx.x;
    if (e < E) {
        int n = (stride == 2) ? (int)((const long long*)dst)[e] : dst[e];
        atomicAdd(&counts[n], 1);
    }
}

__global__ void cursor_init(const int* __restrict__ lofs, const int* __restrict__ partials,
                            int* __restrict__ cursor, int N) {
    int i = blockIdx.x * BLK + threadIdx.x;
    if (i < N) cursor[i] = lofs[i] + partials[i >> 8];
}

__global__ void permscatter(const int* __restrict__ dst, int stride,
                            int* __restrict__ cursor, int* __restrict__ perm, int E) {
    int e = blockIdx.x * BLK + threadIdx.x;
    if (e < E) {
        int n = (stride == 2) ? (int)((const long long*)dst)[e] : dst[e];
        int pos = atomicAdd(&cursor[n], 1);
        perm[pos] = e;
    }
}

// ---- gather-reduce: one wave per node; float4 lanes ----
// qid = lane>>4 selects one of 4 edges per group; fq = lane&15 selects the
// 16B feature quad. One VMEM instruction gathers 4 full rows (1KB) per wave.
__global__ void reduce(const float* __restrict__ msg, const int* __restrict__ perm,
                       const int* __restrict__ lofs, const int* __restrict__ partials,
                       const int* __restrict__ counts, float* __restrict__ out, int N) {
    int node = blockIdx.x * 4 + (threadIdx.x >> 6);
    if (node >= N) return;
    int lane = threadIdx.x & 63;
    int qid  = lane >> 4;          // edge slot 0..3 within a 4-edge group
    int fq   = lane & 15;          // feature quad (features 4*fq .. 4*fq+3)

    int beg   = lofs[node] + partials[node >> 8];
    int deg_i = counts[node];
    int end   = beg + deg_i;

    v4f s4 = {0.f, 0.f, 0.f, 0.f};
    v4f q4 = {0.f, 0.f, 0.f, 0.f};
    v4f m4 = {-FLT_MAX, -FLT_MAX, -FLT_MAX, -FLT_MAX};

    const v4f* __restrict__ msg4 = (const v4f*)msg;

    for (int base = beg; base < end; base += 64) {
        int cnt = end - base;
        if (cnt > 64) cnt = 64;
        int idx = base + lane;
        if (idx >= end) idx = end - 1;          // clamp: wave-uniform loop bound
        int eid_l = perm[idx];

        int j = 0;
        for (; j + 8 <= cnt; j += 8) {          // 8 edges (8KB) in flight
            int ea = __shfl(eid_l, j + qid);
            int eb = __shfl(eid_l, j + 4 + qid);
            v4f va = __builtin_nontemporal_load(msg4 + (((long long)ea << 4) + fq));
            v4f vb = __builtin_nontemporal_load(msg4 + (((long long)eb << 4) + fq));
            s4 += va; q4 += va * va; m4 = fmax4(m4, va);
            s4 += vb; q4 += vb * vb; m4 = fmax4(m4, vb);
        }
        int rem = cnt - j;                       // 0..7 edges left
        if (rem > 0) {
            int sa = j + qid;
            int ea = __shfl(eid_l, (sa < cnt) ? sa : (cnt - 1));
            v4f va = __builtin_nontemporal_load(msg4 + (((long long)ea << 4) + fq));
            if (sa < cnt) { s4 += va; q4 += va * va; m4 = fmax4(m4, va); }
            if (rem > 4) {
                int sb = j + 4 + qid;
                int eb = __shfl(eid_l, (sb < cnt) ? sb : (cnt - 1));
                v4f vb = __builtin_nontemporal_load(msg4 + (((long long)eb << 4) + fq));
                if (sb < cnt) { s4 += vb; q4 += vb * vb; m4 = fmax4(m4, vb); }
            }
        }
    }

    // fold the 4 edge-slots: butterfly over lane bits 4 and 5
    #pragma unroll
    for (int off = 16; off <= 32; off <<= 1) {
        s4.x += __shfl_xor(s4.x, off); s4.y += __shfl_xor(s4.y, off);
        s4.z += __shfl_xor(s4.z, off); s4.w += __shfl_xor(s4.w, off);
        q4.x += __shfl_xor(q4.x, off); q4.y += __shfl_xor(q4.y, off);
        q4.z += __shfl_xor(q4.z, off); q4.w += __shfl_xor(q4.w, off);
        m4.x = fmaxf(m4.x, __shfl_xor(m4.x, off));
        m4.y = fmaxf(m4.y, __shfl_xor(m4.y, off));
        m4.z = fmaxf(m4.z, __shfl_xor(m4.z, off));
        m4.w = fmaxf(m4.w, __shfl_xor(m4.w, off));
    }

    if (qid == 0) {                              // lanes 0..15 hold the totals
        float deg = fmaxf((float)deg_i, 1.0f);
        v4f mean = s4 / deg;
        v4f var  = q4 / deg - mean * mean;
        var.x = fmaxf(var.x, 0.f); var.y = fmaxf(var.y, 0.f);
        var.z = fmaxf(var.z, 0.f); var.w = fmaxf(var.w, 0.f);
        v4f stdv;
        stdv.x = sqrtf(var.x + 1e-8f); stdv.y = sqrtf(var.y + 1e-8f);
        stdv.z = sqrtf(var.z + 1e-8f); stdv.w = sqrtf(var.w + 1e-8f);
        v4f mx = m4;
        if (deg_i == 0) { mx.x = 0.f; mx.y = 0.f; mx.z = 0.f; mx.w = 0.f; }

        v4f* bo = (v4f*)(out + (long long)node * 256);
        __builtin_nontemporal_store(s4,   bo + fq);        // sum
        __builtin_nontemporal_store(mean, bo + 16 + fq);   // mean
        __builtin_nontemporal_store(mx,   bo + 32 + fq);   // max
        __builtin_nontemporal_store(stdv, bo + 48 + fq);   // std
    }
}

extern "C" void kernel_launch(void* const* d_in, const int* in_sizes, int n_in,
                              void* d_out, int out_size, void* d_ws, size_t ws_size,
                              hipStream_t stream) {
    const float* msg = (const float*)d_in[0];
    const int*   dst = (const int*)d_in[1];
    float* out = (float*)d_out;

    int E = in_sizes[0] / 64;                 // 1,600,000
    int N = out_size / 256;                   // 100,000
    int stride = (in_sizes[1] == 2 * E) ? 2 : 1;   // int64-as-int32-pairs defense

    int* counts   = (int*)d_ws;
    int* lofs     = counts + N;
    int* partials = lofs + N;                 // 512
    int* perm     = partials + 512;           // E
    int* extra    = perm + E;                 // rank[E] (rank path) or cursor[N] (fallback)

    int NB_N = (N + BLK - 1) / BLK;           // 391 (<= 512 required for scan2)
    int NB_E = (E + BLK - 1) / BLK;
    int NT_P = ((E + 1) >> 1);                // pair-threads (covers odd tail)
    int NB_P = (NT_P + BLK - 1) / BLK;

    size_t need_rank = ((size_t)2 * N + 512 + (size_t)2 * E) * sizeof(int);

    zero_counts<<<NB_N, BLK, 0, stream>>>(counts, N);

    if (ws_size >= need_rank) {
        // ---- single-atomic-pass counting sort ----
        int* rank = extra;
        hist_rank<<<NB_P, BLK, 0, stream>>>(dst, stride, counts, rank, E);
        scan1<<<NB_N, BLK, 0, stream>>>(counts, lofs, partials, N);
        scan2<<<1, 512, 0, stream>>>(partials, NB_N);
        scatter_rank<<<NB_P, BLK, 0, stream>>>(dst, stride, lofs, partials, rank, perm, E);
    } else {
        // ---- fallback: two-atomic-pass path ----
        int* cursor = extra;
        hist<<<NB_E, BLK, 0, stream>>>(dst, stride, counts, E);
        scan1<<<NB_N, BLK, 0, stream>>>(counts, lofs, partials, N);
        scan2<<<1, 512, 0, stream>>>(partials, NB_N);
        cursor_init<<<NB_N, BLK, 0, stream>>>(lofs, partials, cursor, N);
        permscatter<<<NB_E, BLK, 0, stream>>>(dst, stride, cursor, perm, E);
    }

    reduce<<<(N + 3) / 4, BLK, 0, stream>>>(msg, perm, lofs, partials, counts, out, N);
}